// Round 6
// baseline (821.303 us; speedup 1.0000x reference)
//
#include <hip/hip_runtime.h>

typedef short short8 __attribute__((ext_vector_type(8)));
typedef float f32x16 __attribute__((ext_vector_type(16)));

// Problem constants
#define DIMV   64
#define NEMB   1024
#define NROWS  262144          // B*T = 2048*128
#define DECAYF 0.99f
#define OMDF   0.01f
#define EPSF   1e-5f

// d_out layout (floats): quantize | loss | new_embed | new_cluster_size | new_embed_avg
#define OQ   0
#define OL   16777216
#define OE   16777217
#define ONC  16842753
#define OA   16843777
// EH/EL (bf16 split codebook, MFMA-B-fragment order) live in the d_out tail:
// written by vq_prep_b, read by vq_main, then overwritten by finalA/finalB.
#define OEH  16777216
#define OEL  (16777216 + 32768)

// d_ws layout (floats)
#define WS_E2     0        // 1024: ||e_k||^2
#define WS_ET     1024     // 65536: embed transposed [k][d] fp32
#define WS_LOSS   66560    // 1024: loss partial array (contention-free-ish)
#define WS_TOTAL  67584    // 1
#define WS_STRIPE 67600    // P stripes of [1024 counts | 65536 esum k-major]
#define STRIDE_S  66560    // floats per stripe

// RNE float->bf16 (no NaN in data), and back
__device__ __forceinline__ unsigned short f2bf(float f) {
    unsigned u = __float_as_uint(f);
    u = u + 0x7FFFu + ((u >> 16) & 1u);
    return (unsigned short)(u >> 16);
}
__device__ __forceinline__ float bf2f(unsigned short h) {
    return __uint_as_float(((unsigned)h) << 16);
}

// ---------------------------------------------------------------- prep: transpose embed -> et[k][d]
__global__ void vq_prep(const float* __restrict__ embed, float* __restrict__ et)
{
    int idx = blockIdx.x * 256 + threadIdx.x;   // < 65536, idx = d*1024 + k
    int d = idx >> 10;
    int k = idx & (NEMB - 1);
    et[k * DIMV + d] = embed[idx];
}

__global__ void vq_e2(const float* __restrict__ et, float* __restrict__ e2)
{
    int k = blockIdx.x * 256 + threadIdx.x;   // k < 1024
    const float4* ep = (const float4*)(et + k * DIMV);
    float s = 0.f;
    #pragma unroll
    for (int i = 0; i < 16; i++) {
        float4 v = ep[i];
        s = fmaf(v.x, v.x, fmaf(v.y, v.y, fmaf(v.z, v.z, fmaf(v.w, v.w, s))));
    }
    e2[k] = s;
}

// ---------------------------------------------------------------- prep: split codebook into bf16 hi/lo,
// pre-swizzled into 32x32x16 MFMA B-fragment order:
// frag(nt,s): lane L, elem j  <->  B[k = s*16 + (L>>5)*8 + j][n = nt*32 + (L&31)]
__global__ void vq_prep_b(const float* __restrict__ embed,
                          unsigned short* __restrict__ eh,
                          unsigned short* __restrict__ el)
{
    int t = blockIdx.x * 256 + threadIdx.x;    // 0..65535
    int j  = t & 7;
    int L  = (t >> 3) & 63;
    int s  = (t >> 9) & 3;
    int nt = t >> 11;                          // 0..31
    int d    = s * 16 + (L >> 5) * 8 + j;
    int code = nt * 32 + (L & 31);
    float e = embed[d * NEMB + code];
    unsigned short hb = f2bf(e);
    eh[t] = hb;
    el[t] = f2bf(e - bf2f(hb));
}

// ---------------------------------------------------------------- main
__global__ __launch_bounds__(256, 2) void vq_main(
    const float* __restrict__ x, const int* __restrict__ mask,
    const unsigned short* __restrict__ eh, const unsigned short* __restrict__ el,
    const float* __restrict__ et, const float* __restrict__ e2g,
    float* __restrict__ out, float* __restrict__ stripes,
    float* __restrict__ lossarr, int P)
{
    const int tid  = threadIdx.x;
    const int lane = tid & 63;
    const int wid  = tid >> 6;
    const int wbase = blockIdx.x * 256 + wid * 64;   // wave's first row
    const int lm = lane & 31;    // m (A) / n (B) within tile
    const int lh = lane >> 5;    // k-half selector

    // stripe assignment: adjacent waves -> different stripes
    float* scnt  = stripes + (size_t)((blockIdx.x * 4 + wid) & (P - 1)) * STRIDE_S;
    float* sesum = scnt + 1024;

    // ---- A fragments: xh/xl for 2 M-tiles x 4 K-steps. A[m=lane&31][k=(lane>>5)*8+j]
    short8 ah[2][4], al[2][4];
    #pragma unroll
    for (int mt = 0; mt < 2; mt++) {
        const float* xr = x + (size_t)(wbase + mt * 32 + lm) * DIMV + lh * 8;
        #pragma unroll
        for (int s = 0; s < 4; s++) {
            const float* xp = xr + s * 16;
            #pragma unroll
            for (int j = 0; j < 8; j++) {
                float f = xp[j];
                unsigned short hb = f2bf(f);
                ah[mt][s][j] = (short)hb;
                al[mt][s][j] = (short)f2bf(f - bf2f(hb));
            }
        }
    }

    // per-lane top-2 keys per (mtile, acc-reg); key = (q<<10)|k, q = trunc(2048*(e2-2dot))
    int b1[2][16], b2[2][16];
    #pragma unroll
    for (int mt = 0; mt < 2; mt++)
        #pragma unroll
        for (int r = 0; r < 16; r++) { b1[mt][r] = 0x7FFFFFFF; b2[mt][r] = 0x7FFFFFFF; }

    const short8* ehf = (const short8*)eh;
    const short8* elf = (const short8*)el;

    for (int nt = 0; nt < 32; nt++) {
        short8 bh[4], bl[4];
        #pragma unroll
        for (int s = 0; s < 4; s++) {
            bh[s] = ehf[(nt * 4 + s) * 64 + lane];
            bl[s] = elf[(nt * 4 + s) * 64 + lane];
        }
        const int   klane = nt * 32 + lm;
        const float e2s   = e2g[klane] * 2048.0f;

        f32x16 acc0, acc1;
        #pragma unroll
        for (int i = 0; i < 16; i++) { acc0[i] = 0.0f; acc1[i] = 0.0f; }

        #pragma unroll
        for (int s = 0; s < 4; s++) {   // pass hh
            acc0 = __builtin_amdgcn_mfma_f32_32x32x16_bf16(ah[0][s], bh[s], acc0, 0, 0, 0);
            acc1 = __builtin_amdgcn_mfma_f32_32x32x16_bf16(ah[1][s], bh[s], acc1, 0, 0, 0);
        }
        #pragma unroll
        for (int s = 0; s < 4; s++) {   // pass hl
            acc0 = __builtin_amdgcn_mfma_f32_32x32x16_bf16(ah[0][s], bl[s], acc0, 0, 0, 0);
            acc1 = __builtin_amdgcn_mfma_f32_32x32x16_bf16(ah[1][s], bl[s], acc1, 0, 0, 0);
        }
        #pragma unroll
        for (int s = 0; s < 4; s++) {   // pass lh
            acc0 = __builtin_amdgcn_mfma_f32_32x32x16_bf16(al[0][s], bh[s], acc0, 0, 0, 0);
            acc1 = __builtin_amdgcn_mfma_f32_32x32x16_bf16(al[1][s], bh[s], acc1, 0, 0, 0);
        }

        #pragma unroll
        for (int r = 0; r < 16; r++) {
            int q0   = (int)fmaf(acc0[r], -4096.0f, e2s);     // 2048*(e2-2dot), trunc
            int key0 = (int)(((unsigned)q0) << 10) | klane;
            int lo0 = min(b1[0][r], key0), hi0 = max(b1[0][r], key0);
            b1[0][r] = lo0; b2[0][r] = min(b2[0][r], hi0);

            int q1   = (int)fmaf(acc1[r], -4096.0f, e2s);
            int key1 = (int)(((unsigned)q1) << 10) | klane;
            int lo1 = min(b1[1][r], key1), hi1 = max(b1[1][r], key1);
            b1[1][r] = lo1; b2[1][r] = min(b2[1][r], hi1);
        }
    }

    // ---- cross-lane reduction (per half-wave = 32 lanes sharing a row) ----
    int sm1 = 0x7FFFFFFF, sm2 = 0x7FFFFFFF, sc = 1;
    unsigned long long hm = (lane < 32) ? 0xFFFFFFFFull : 0xFFFFFFFF00000000ull;
    #pragma unroll
    for (int mt = 0; mt < 2; mt++) {
        #pragma unroll
        for (int r = 0; r < 16; r++) {
            int v1 = b1[mt][r], v2 = b2[mt][r];
            #pragma unroll
            for (int m = 1; m <= 16; m <<= 1) {
                int o1 = __shfl_xor(v1, m, 64);
                int o2 = __shfl_xor(v2, m, 64);
                int lo = min(v1, o1), hi = max(v1, o1);
                v1 = lo;
                v2 = min(min(v2, o2), hi);
            }
            int thr = (v1 >> 10) + 41;   // window = 41/2048 ~= 0.02
            bool in1 = (b1[mt][r] >> 10) <= thr;
            bool in2 = (b2[mt][r] >> 10) <= thr;
            unsigned long long B1 = __ballot(in1), B2 = __ballot(in2);
            int cnt = (int)__popcll(B1 & hm) + (int)__popcll(B2 & hm);
            int w1a = __shfl(v1, 0, 64),  w2a = __shfl(v2, 0, 64),  ca = __shfl(cnt, 0, 64);
            int w1b = __shfl(v1, 32, 64), w2b = __shfl(v2, 32, 64), cb = __shfl(cnt, 32, 64);
            int r0 = mt * 32 + (r & 3) + 8 * (r >> 2);
            if (lane == r0)     { sm1 = w1a; sm2 = w2a; sc = ca; }
            if (lane == r0 + 4) { sm1 = w1b; sm2 = w2b; sc = cb; }
        }
    }

    // ---- per-lane epilogue: lane owns row wbase+lane ----
    const int row = wbase + lane;
    float4 xv[16];
    {
        const float4* xp = (const float4*)(x + (size_t)row * DIMV);
        #pragma unroll
        for (int i = 0; i < 16; i++) xv[i] = xp[i];
    }

    int kw = sm1 & 1023;
    if (sc >= 2) {
        float x2 = 0.f;
        #pragma unroll
        for (int i = 0; i < 16; i++)
            x2 += xv[i].x * xv[i].x + xv[i].y * xv[i].y + xv[i].z * xv[i].z + xv[i].w * xv[i].w;

        auto fdist = [&](int k) -> float {
            const float4* ep = (const float4*)(et + (k << 6));
            float ax = 0.f, ay = 0.f, az = 0.f, aw = 0.f;
            #pragma unroll
            for (int i = 0; i < 16; i++) {
                float4 ev = ep[i];
                ax = fmaf(xv[i].x, ev.x, ax);
                ay = fmaf(xv[i].y, ev.y, ay);
                az = fmaf(xv[i].z, ev.z, az);
                aw = fmaf(xv[i].w, ev.w, aw);
            }
            float dot = (ax + ay) + (az + aw);
            return (x2 - 2.0f * dot) + e2g[k];
        };

        if (sc >= 3) {
            float bd = 3.4e38f; int bk = 0;
            for (int k = 0; k < NEMB; k++) {
                float d = fdist(k);
                if (d < bd) { bd = d; bk = k; }
            }
            kw = bk;
        } else {
            int k2 = sm2 & 1023;
            float d1 = fdist(kw);
            float d2 = fdist(k2);
            if (d2 < d1 || (d2 == d1 && k2 < kw)) kw = k2;
        }
    }

    const bool valid = (mask[row] == 0);   // valid = ~mask
    float sq = 0.f;
    float4* qp = (float4*)(out + OQ + (size_t)row * DIMV);
    const float4* erow = (const float4*)(et + (kw << 6));
    #pragma unroll
    for (int i = 0; i < 16; i++) {
        float4 xvv = xv[i];
        float4 ev  = erow[i];
        float q0 = xvv.x + (ev.x - xvv.x);
        float q1 = xvv.y + (ev.y - xvv.y);
        float q2 = xvv.z + (ev.z - xvv.z);
        float q3 = xvv.w + (ev.w - xvv.w);
        float4 q4 = {q0, q1, q2, q3};
        qp[i] = q4;
        float d0 = q0 - xvv.x, d1 = q1 - xvv.y, d2 = q2 - xvv.z, d3 = q3 - xvv.w;
        sq += d0 * d0 + d1 * d1 + d2 * d2 + d3 * d3;
    }
    if (valid) atomicAdd(&scnt[kw], 1.0f);

    // ---- wave-transposed EMA scatter into this wave's stripe:
    // one atomic instruction per valid row; 64 lanes = row's 64 contiguous dims.
    unsigned long long vmask = __ballot(valid);
    #pragma unroll 4
    for (int j = 0; j < 64; j++) {
        if ((vmask >> j) & 1ull) {
            int kj = __shfl(kw, j, 64);
            float xjl = x[(size_t)(wbase + j) * DIMV + lane];   // coalesced, cache-hot
            atomicAdd(&sesum[(kj << 6) + lane], xjl);
        }
    }

    float v = valid ? sq : 0.0f;
    #pragma unroll
    for (int off = 32; off > 0; off >>= 1) v += __shfl_down(v, off, 64);
    if (lane == 0) atomicAdd(&lossarr[(blockIdx.x * 4 + wid) & 1023], v);
}

// ---------------------------------------------------------------- finalize A
__global__ __launch_bounds__(1024) void vq_finalA(
    const float* __restrict__ cluster_size, const float* __restrict__ stripes,
    const float* __restrict__ lossarr, float* __restrict__ out,
    float* __restrict__ total_ws, int P)
{
    __shared__ float s1[1024];
    __shared__ float s2[1024];
    __shared__ float s3[1024];
    int k = threadIdx.x;
    float c = 0.f;
    for (int s = 0; s < P; s++) c += stripes[(size_t)s * STRIDE_S + k];
    float ncs = cluster_size[k] * DECAYF + OMDF * c;
    out[ONC + k] = ncs;
    s1[k] = ncs; s2[k] = c; s3[k] = lossarr[k];
    __syncthreads();
    for (int off = 512; off > 0; off >>= 1) {
        if (k < off) { s1[k] += s1[k + off]; s2[k] += s2[k + off]; s3[k] += s3[k + off]; }
        __syncthreads();
    }
    if (k == 0) {
        total_ws[0] = s1[0];
        out[OL] = s3[0] / (s2[0] * (float)DIMV);
    }
}

// ---------------------------------------------------------------- finalize B (esum striped, k-major)
__global__ void vq_finalB(const float* __restrict__ embed_avg,
                          const float* __restrict__ stripes,
                          float* __restrict__ out,
                          const float* __restrict__ total_ws, int P)
{
    int idx = blockIdx.x * 256 + threadIdx.x;  // < 65536, idx = d*1024 + k
    int k = idx & (NEMB - 1);
    int d = idx >> 10;
    float es = 0.f;
    for (int s = 0; s < P; s++)
        es += stripes[(size_t)s * STRIDE_S + 1024 + (k << 6) + d];
    float avg = embed_avg[idx] * DECAYF + OMDF * es;
    out[OA + idx] = avg;
    float ncs   = out[ONC + k];
    float total = *total_ws;
    float sm = (ncs + EPSF) / (total + (float)NEMB * EPSF) * total;
    out[OE + idx] = avg / sm;
}

// ---------------------------------------------------------------- launcher
extern "C" void kernel_launch(void* const* d_in, const int* in_sizes, int n_in,
                              void* d_out, int out_size, void* d_ws, size_t ws_size,
                              hipStream_t stream)
{
    const float* x            = (const float*)d_in[0];
    const int*   mask         = (const int*)d_in[1];
    const float* embed        = (const float*)d_in[2];
    const float* cluster_size = (const float*)d_in[3];
    const float* embed_avg    = (const float*)d_in[4];
    float* out = (float*)d_out;
    float* ws  = (float*)d_ws;

    unsigned short* eh = (unsigned short*)(out + OEH);
    unsigned short* el = (unsigned short*)(out + OEL);

    // choose stripe count P (power of 2, <=16) that fits the workspace
    size_t avail = ws_size / 4;   // floats
    int P = 1;
    while (P < 16 && (size_t)WS_STRIPE + (size_t)(P * 2) * STRIDE_S <= avail) P <<= 1;

    // zero loss array + total + all stripes
    size_t zfloats = (size_t)WS_STRIPE + (size_t)P * STRIDE_S - WS_LOSS;
    hipMemsetAsync(ws + WS_LOSS, 0, zfloats * sizeof(float), stream);

    vq_prep<<<65536 / 256, 256, 0, stream>>>(embed, ws + WS_ET);
    vq_e2<<<NEMB / 256, 256, 0, stream>>>(ws + WS_ET, ws + WS_E2);
    vq_prep_b<<<65536 / 256, 256, 0, stream>>>(embed, eh, el);
    vq_main<<<NROWS / 256, 256, 0, stream>>>(x, mask, eh, el, ws + WS_ET, ws + WS_E2,
                                             out, ws + WS_STRIPE, ws + WS_LOSS, P);
    vq_finalA<<<1, 1024, 0, stream>>>(cluster_size, ws + WS_STRIPE, ws + WS_LOSS,
                                      out, ws + WS_TOTAL, P);
    vq_finalB<<<65536 / 256, 256, 0, stream>>>(embed_avg, ws + WS_STRIPE, out,
                                               ws + WS_TOTAL, P);
}